// Round 1
// 205.294 us; speedup vs baseline: 1.0639x; 1.0639x over previous
//
#include <hip/hip_runtime.h>
#include <math.h>

#define LSEQ 4096
#define HDIM 768
#define NHEAD 12

using v4f    = __attribute__((ext_vector_type(4))) float;
using f4     = __attribute__((ext_vector_type(4))) float;
using short8 = __attribute__((ext_vector_type(8))) short;
using u32x4  = __attribute__((ext_vector_type(4))) unsigned int;

#if __has_builtin(__builtin_amdgcn_exp2f)
#define EXP2F(x) __builtin_amdgcn_exp2f(x)
#else
#define EXP2F(x) exp2f(x)
#endif

// async global->LDS, 16B per lane; LDS dest is wave-uniform base + lane*16
#define GLOAD_LDS16(g, l)                                                  \
  __builtin_amdgcn_global_load_lds(                                       \
      (const __attribute__((address_space(1))) unsigned int*)(g),         \
      (__attribute__((address_space(3))) unsigned int*)(l), 16, 0, 0)

// v_cvt_pk_bf16_f32: d.lo16 = bf16_rne(lo), d.hi16 = bf16_rne(hi). 1 VALU op
// for 2 conversions vs 4 integer ops/value for the manual RNE sequence.
__device__ __forceinline__ unsigned cvt_pk_bf16(float lo, float hi) {
  unsigned d;
  asm("v_cvt_pk_bf16_f32 %0, %1, %2" : "=v"(d) : "v"(lo), "v"(hi));
  return d;
}

__device__ __forceinline__ unsigned short f2bf(float f) {
  union { float f; unsigned u; } v; v.f = f;
  unsigned r = v.u + 0x7fffu + ((v.u >> 16) & 1u);
  return (unsigned short)(r >> 16);
}

// Convert 8 fp32 -> bf16x8 via 4x v_cvt_pk_bf16_f32 (was 32 integer ops).
__device__ __forceinline__ short8 cvt8(f4 a, f4 b) {
  union { unsigned u[4]; short8 s; } r;
  r.u[0] = cvt_pk_bf16(a[0], a[1]);
  r.u[1] = cvt_pk_bf16(a[2], a[3]);
  r.u[2] = cvt_pk_bf16(b[0], b[1]);
  r.u[3] = cvt_pk_bf16(b[2], b[3]);
  return r.s;
}

// ---------------------------------------------------------------------------
// QKV projection. Y = X W^T + b (fp32 in, bf16 out). Tile 128x128, BK=32.
// Q,K dst: [NH][L][64]. V dst: [NH][64][L] transposed AND key-permuted within
// 32-blocks (pos = ((k&15)>>2)*8 + ((k>>4)&1)*4 + (k&3)) so attn's b128
// V-fragments feed K=32 PV MFMAs whose B operand is P in registers.
// ---------------------------------------------------------------------------
__global__ __launch_bounds__(256, 2) void proj_gemm(
    const float* __restrict__ Xq, const float* __restrict__ Xk,
    const float* __restrict__ Xv,
    const float* __restrict__ Wq, const float* __restrict__ Wk,
    const float* __restrict__ Wv,
    const float* __restrict__ bq, const float* __restrict__ bk,
    const float* __restrict__ bv,
    unsigned short* __restrict__ dst_base)
{
  __shared__ __align__(16) unsigned short a_lds[128 * 32];
  __shared__ __align__(16) unsigned short b_lds[128 * 32];
  __shared__ __align__(16) unsigned short c_lds[64 * 136];

  const int id = blockIdx.x;                 // 0..575
  const int xcd = id & 7, local = id >> 3;
  const int grp = local / 6, bnIdx = local % 6;
  const int G = grp * 8 + xcd;               // 0..95 bijective
  const int z = G >> 5;
  const int bm = (G & 31) * 128, bn = bnIdx * 128;

  const float* X = (z == 0) ? Xq : ((z == 1) ? Xk : Xv);
  const float* W = (z == 0) ? Wq : ((z == 1) ? Wk : Wv);
  const float* bias = (z == 0) ? bq : ((z == 1) ? bk : bv);
  unsigned short* dst = dst_base + (size_t)z * NHEAD * LSEQ * 64;

  const int tid = threadIdx.x;
  const int wave = tid >> 6, lane = tid & 63;
  const int quad = lane >> 4, l16 = lane & 15;
  const int wm = (wave >> 1) * 64, wn = (wave & 1) * 64;

  v4f acc[4][4];
  for (int i = 0; i < 4; ++i)
    for (int j = 0; j < 4; ++j)
      acc[i][j] = (v4f){0.f, 0.f, 0.f, 0.f};

  const int row_s = tid >> 2;
  const int c8_s = (tid & 3) * 8;

  const float* xrow[2]; const float* wrow[2];
#pragma unroll
  for (int s = 0; s < 2; ++s) {
    xrow[s] = X + (size_t)(bm + row_s + 64 * s) * HDIM + c8_s;
    wrow[s] = W + (size_t)(bn + row_s + 64 * s) * HDIM + c8_s;
  }

  f4 pa[2][2], pw[2][2];
#pragma unroll
  for (int s = 0; s < 2; ++s) {
    pa[s][0] = *(const f4*)(xrow[s]);     pa[s][1] = *(const f4*)(xrow[s] + 4);
    pw[s][0] = *(const f4*)(wrow[s]);     pw[s][1] = *(const f4*)(wrow[s] + 4);
  }

  for (int k0 = 0; k0 < HDIM; k0 += 32) {
    __syncthreads();
#pragma unroll
    for (int s = 0; s < 2; ++s) {
      *(short8*)&a_lds[(row_s + 64 * s) * 32 + c8_s] = cvt8(pa[s][0], pa[s][1]);
      *(short8*)&b_lds[(row_s + 64 * s) * 32 + c8_s] = cvt8(pw[s][0], pw[s][1]);
    }
    __syncthreads();

    if (k0 + 32 < HDIM) {
#pragma unroll
      for (int s = 0; s < 2; ++s) {
        pa[s][0] = *(const f4*)(xrow[s] + k0 + 32);
        pa[s][1] = *(const f4*)(xrow[s] + k0 + 36);
        pw[s][0] = *(const f4*)(wrow[s] + k0 + 32);
        pw[s][1] = *(const f4*)(wrow[s] + k0 + 36);
      }
    }

    short8 af[4], bfr[4];
    for (int i = 0; i < 4; ++i)
      af[i] = *(const short8*)&a_lds[(wm + i * 16 + l16) * 32 + quad * 8];
    for (int j = 0; j < 4; ++j)
      bfr[j] = *(const short8*)&b_lds[(wn + j * 16 + l16) * 32 + quad * 8];
    if (z == 2) {
      for (int i = 0; i < 4; ++i)
        for (int j = 0; j < 4; ++j)
          acc[i][j] = __builtin_amdgcn_mfma_f32_16x16x32_bf16(bfr[j], af[i], acc[i][j], 0, 0, 0);
    } else {
      for (int i = 0; i < 4; ++i)
        for (int j = 0; j < 4; ++j)
          acc[i][j] = __builtin_amdgcn_mfma_f32_16x16x32_bf16(af[i], bfr[j], acc[i][j], 0, 0, 0);
    }
  }

  for (int p = 0; p < 2; ++p) {
    __syncthreads();
    if (z == 2) {
      if ((wave & 1) == p) {
        // C^T: row = d-local, col = seq-local. Apply the key permutation
        // within 32-blocks while writing c_lds: s = (i&1)*16 + l16 ->
        // s' = (l16>>2)*8 + (i&1)*4 + (l16&3).
        for (int j = 0; j < 4; ++j)
          for (int r = 0; r < 4; ++r) {
            float bvv = bias[bn + wn + j * 16 + quad * 4 + r];
            int row = j * 16 + quad * 4 + r;
            for (int i = 0; i < 4; ++i) {
              int colp = wm + (i >> 1) * 32 + (l16 >> 2) * 8 + (i & 1) * 4 + (l16 & 3);
              c_lds[row * 136 + colp] = f2bf(acc[i][j][r] + bvv);
            }
          }
      }
    } else {
      if ((wave >> 1) == p) {
        for (int j = 0; j < 4; ++j) {
          float bvv = bias[bn + wn + j * 16 + l16];
          for (int i = 0; i < 4; ++i)
            for (int r = 0; r < 4; ++r)
              c_lds[(i * 16 + quad * 4 + r) * 136 + wn + j * 16 + l16] =
                  f2bf(acc[i][j][r] + bvv);
        }
      }
    }
    __syncthreads();
    int row = tid >> 2, c = tid & 3;
    const unsigned short* srow = &c_lds[row * 136 + c * 32];
    if (z == 2) {
      int n = bn + p * 64 + row;
      int hh = n >> 6, d = n & 63;
      unsigned short* drow = dst + ((size_t)hh * 64 + d) * LSEQ + bm + c * 32;
      for (int q8 = 0; q8 < 4; ++q8)
        *(u32x4*)(drow + q8 * 8) = *(const u32x4*)(srow + q8 * 8);
    } else {
      int m = bm + p * 64 + row;
      int nbase = bn + c * 32;
      int hh = nbase >> 6, d = nbase & 63;
      unsigned short* drow = dst + ((size_t)hh * LSEQ + m) * 64 + d;
      for (int q8 = 0; q8 < 4; ++q8)
        *(u32x4*)(drow + q8 * 8) = *(const u32x4*)(srow + q8 * 8);
    }
  }
}

// ---------------------------------------------------------------------------
// Flash attention, S^T formulation: mfma(kf,qf) -> S^T whose C-layout IS the
// B-operand layout for PV (P never round-trips LDS). PV = mfma(V^T-frag,
// P-regs) -> O^T. V key-permuted in ws so b128 frags feed K=32 MFMA.
// 4 waves = (q-half qg x key-half kh); no-max softmax; double-buffered async
// staging, one barrier/tile; merge of key-halves reuses staging LDS.
// Softmax VALU diet: v_cvt_pk_bf16_f32 packs P (RNE), and the P row-sum
// (softmax denominator) is computed on the MATRIX pipe via a ones-row MFMA
// against the packed bf16 P — keeps numerator/denominator rounding-consistent
// and deletes 16 v_add + 2 shuffles from the VALU path.
// grid = (64, 12), block = 256.
// ---------------------------------------------------------------------------
__global__ __launch_bounds__(256, 3) void attn(
    const unsigned short* __restrict__ Q, const unsigned short* __restrict__ K,
    const unsigned short* __restrict__ Vt, const float* __restrict__ mask,
    float* __restrict__ out)
{
  __shared__ __align__(16) unsigned short smem[4 * 64 * 64];  // 32 KB
  // k buf b: smem + b*4096 ; vt buf b: smem + 8192 + b*4096   (shorts)

  const int h = blockIdx.y;
  const int qt = blockIdx.x;
  const int tid = threadIdx.x;
  const int wave = tid >> 6, lane = tid & 63;
  const int quad = lane >> 4, l16 = lane & 15;
  const int qg = wave & 1, kh = wave >> 1;

  const unsigned short* Qh  = Q  + (size_t)h * LSEQ * 64;
  const unsigned short* Kh  = K  + (size_t)h * LSEQ * 64;
  const unsigned short* Vth = Vt + (size_t)h * 64 * LSEQ;

  // Async staging: wave stages segs wave*2+s (1 KB each) of both
  // K [key][d] (chunk^(key&7)) and V^T [d][key] (chunk^(d&7)).
  const unsigned short* ksrc[2]; const unsigned short* vsrc[2];
  unsigned short* kdst[2]; unsigned short* vdst[2];
#pragma unroll
  for (int s = 0; s < 2; ++s) {
    int seg = wave * 2 + s;
    int rl = lane >> 3, cc = (lane & 7) ^ rl;
    ksrc[s] = Kh + (size_t)(seg * 8 + rl) * 64 + cc * 8;
    vsrc[s] = Vth + (size_t)(seg * 8 + rl) * LSEQ + cc * 8;
    kdst[s] = smem + seg * 512;
    vdst[s] = smem + 8192 + seg * 512;
  }

  // Q fragments (B-operand for QK): 32 q-rows (qg half), both d-chunks.
  short8 qf[2][2];
#pragma unroll
  for (int qi = 0; qi < 2; ++qi)
#pragma unroll
    for (int c = 0; c < 2; ++c)
      qf[qi][c] = *(const short8*)(Qh + (size_t)(qt * 64 + qg * 32 + qi * 16 + l16) * 64 +
                                   c * 32 + quad * 8);

  // ones fragment (bf16 1.0) for the denominator MFMA
  short8 ones8;
#pragma unroll
  for (int i = 0; i < 8; ++i) ones8[i] = (short)0x3F80;

  v4f acc[2][4];   // O^T: [qi][d-tile j], C-layout col=q(l16), row=d(quad*4+r)
  v4f lacc[2];     // denominator: D[row][q] = sum_k P[k][q] (rows all equal)
#pragma unroll
  for (int qi = 0; qi < 2; ++qi) {
    for (int j = 0; j < 4; ++j) acc[qi][j] = (v4f){0.f, 0.f, 0.f, 0.f};
    lacc[qi] = (v4f){0.f, 0.f, 0.f, 0.f};
  }

  // prologue: tile 0 into buf 0
#pragma unroll
  for (int s = 0; s < 2; ++s) { GLOAD_LDS16(ksrc[s], kdst[s]); GLOAD_LDS16(vsrc[s], vdst[s]); }

#pragma unroll 2
  for (int kt = 0; kt < 64; ++kt) {
    const int key0 = kt * 64;
    const int buf = kt & 1, nbuf = (kt + 1) & 1;

    __syncthreads();  // own-wave vmcnt(0) drain + all waves done with buf[nbuf]

    if (kt < 63) {
      size_t ko = (size_t)(key0 + 64) * 64;
#pragma unroll
      for (int s = 0; s < 2; ++s) {
        GLOAD_LDS16(ksrc[s] + ko, kdst[s] + nbuf * 4096);
        GLOAD_LDS16(vsrc[s] + (key0 + 64), vdst[s] + nbuf * 4096);
      }
    }

    // mask per key (additive, broadcast over q): lane's keys = quad*4+r
    f4 mvs[2];
#pragma unroll
    for (int k2 = 0; k2 < 2; ++k2)
      mvs[k2] = *(const f4*)(mask + key0 + kh * 32 + k2 * 16 + quad * 4) * 1.44269504f;

    // K fragments (A-operand): row = key, 4 reads hoisted over qi
    const unsigned short* kb = smem + buf * 4096;
    short8 kf[2][2];
#pragma unroll
    for (int k2 = 0; k2 < 2; ++k2)
#pragma unroll
      for (int c = 0; c < 2; ++c) {
        int row = kh * 32 + k2 * 16 + l16;
        kf[k2][c] = *(const short8*)&kb[row * 64 + (((c * 4 + quad) ^ (row & 7)) << 3)];
      }

    // S^T = K Q^T : 8 MFMA; lane holds key=quad*4+r, q=l16
    v4f sacc[2][2];
#pragma unroll
    for (int k2 = 0; k2 < 2; ++k2)
      for (int qi = 0; qi < 2; ++qi) sacc[k2][qi] = (v4f){0.f, 0.f, 0.f, 0.f};
#pragma unroll
    for (int c = 0; c < 2; ++c)
#pragma unroll
      for (int k2 = 0; k2 < 2; ++k2)
#pragma unroll
        for (int qi = 0; qi < 2; ++qi)
          sacc[k2][qi] = __builtin_amdgcn_mfma_f32_16x16x32_bf16(
              kf[k2][c], qf[qi][c], sacc[k2][qi], 0, 0, 0);

    // exp -> pack into PV B-operand registers via v_cvt_pk_bf16_f32 (RNE)
    union { unsigned u[4]; short8 s8; } pb[2];
#pragma unroll
    for (int qi = 0; qi < 2; ++qi)
#pragma unroll
      for (int k2 = 0; k2 < 2; ++k2) {
        float e[4];
#pragma unroll
        for (int r = 0; r < 4; ++r)
          e[r] = EXP2F(fmaf(sacc[k2][qi][r], 0.18033688f, mvs[k2][r]));
        pb[qi].u[k2 * 2 + 0] = cvt_pk_bf16(e[0], e[1]);
        pb[qi].u[k2 * 2 + 1] = cvt_pk_bf16(e[2], e[3]);
      }

    // denominator on the matrix pipe: lacc += ones(16x32) @ P(32x16).
    // Sums the ROUNDED bf16 P (same values PV uses) -> bias cancels in the
    // final normalization exactly as the old truncate-consistent scheme.
#pragma unroll
    for (int qi = 0; qi < 2; ++qi)
      lacc[qi] = __builtin_amdgcn_mfma_f32_16x16x32_bf16(
          ones8, pb[qi].s8, lacc[qi], 0, 0, 0);

    // V^T fragments (A-operand; key-permuted in ws): 4 reads hoisted over qi
    const unsigned short* vb = smem + 8192 + buf * 4096;
    short8 vf[4];
#pragma unroll
    for (int j = 0; j < 4; ++j) {
      int d = j * 16 + l16;
      vf[j] = *(const short8*)&vb[d * 64 + (((kh * 4 + quad) ^ (d & 7)) << 3)];
    }

    // O^T += V^T P^T : 8 MFMA
#pragma unroll
    for (int qi = 0; qi < 2; ++qi)
#pragma unroll
      for (int j = 0; j < 4; ++j)
        acc[qi][j] = __builtin_amdgcn_mfma_f32_16x16x32_bf16(
            vf[j], pb[qi].s8, acc[qi][j], 0, 0, 0);
  }

  // denominator is fully reduced over k by the ones-MFMA: all rows/quads
  // already hold the same per-q sum -> no shuffles needed.
  float lsum[2] = { lacc[0][0], lacc[1][0] };

  // merge key-halves (reuse staging LDS; stride 66 floats -> conflict-light)
  __syncthreads();
  float* mrg = (float*)smem;                 // 64 rows x 66 floats
  float* lsl = mrg + 64 * 66;                // 64 floats
  if (kh == 1) {
#pragma unroll
    for (int qi = 0; qi < 2; ++qi) {
      int qrow = (qg * 2 + qi) * 16 + l16;
#pragma unroll
      for (int j = 0; j < 4; ++j)
#pragma unroll
        for (int r = 0; r < 4; ++r)
          mrg[qrow * 66 + j * 16 + quad * 4 + r] = acc[qi][j][r];
      if (quad == 0) lsl[qrow] = lsum[qi];
    }
  }
  __syncthreads();
  if (kh == 0) {
#pragma unroll
    for (int qi = 0; qi < 2; ++qi) {
      int qrow = (qg * 2 + qi) * 16 + l16;
      float inv = 1.0f / (lsum[qi] + lsl[qrow]);
      int row = qt * 64 + qg * 32 + qi * 16 + l16;
#pragma unroll
      for (int j = 0; j < 4; ++j) {
        f4 o;
#pragma unroll
        for (int r = 0; r < 4; ++r)
          o[r] = (acc[qi][j][r] + mrg[qrow * 66 + j * 16 + quad * 4 + r]) * inv;
        *(f4*)(out + (size_t)row * HDIM + h * 64 + j * 16 + quad * 4) = o;
      }
    }
  }
}

extern "C" void kernel_launch(void* const* d_in, const int* in_sizes, int n_in,
                              void* d_out, int out_size, void* d_ws, size_t ws_size,
                              hipStream_t stream) {
  const float* query = (const float*)d_in[0];
  const float* key   = (const float*)d_in[1];
  const float* value = (const float*)d_in[2];
  const float* mask  = (const float*)d_in[3];
  const float* Wq = (const float*)d_in[4];
  const float* bq = (const float*)d_in[5];
  const float* Wk = (const float*)d_in[6];
  const float* bk = (const float*)d_in[7];
  const float* Wv = (const float*)d_in[8];
  const float* bv = (const float*)d_in[9];
  float* out = (float*)d_out;

  // ws usage: exactly 3 * NHEAD*LSEQ*64 bf16 = 18,874,368 bytes (hard limit —
  // writing 4 bytes past this corrupted a pristine input copy in round 2).
  unsigned short* Qb = (unsigned short*)d_ws;                  // [NH][L][64] bf16
  unsigned short* Kb = Qb + (size_t)NHEAD * LSEQ * 64;         // [NH][L][64] bf16
  unsigned short* Vb = Kb + (size_t)NHEAD * LSEQ * 64;         // [NH][64][L] bf16, key-permuted

  proj_gemm<<<576, 256, 0, stream>>>(
      query, key, value, Wq, Wk, Wv, bq, bk, bv, Qb);
  attn<<<dim3(LSEQ / 64, NHEAD), 256, 0, stream>>>(Qb, Kb, Vb, mask, out);
}

// Round 5
// 205.215 us; speedup vs baseline: 1.0643x; 1.0004x over previous
//
#include <hip/hip_runtime.h>
#include <math.h>

#define LSEQ 4096
#define HDIM 768
#define NHEAD 12

using v4f    = __attribute__((ext_vector_type(4))) float;
using f4     = __attribute__((ext_vector_type(4))) float;
using short8 = __attribute__((ext_vector_type(8))) short;
using u32x4  = __attribute__((ext_vector_type(4))) unsigned int;

#if __has_builtin(__builtin_amdgcn_exp2f)
#define EXP2F(x) __builtin_amdgcn_exp2f(x)
#else
#define EXP2F(x) exp2f(x)
#endif

// async global->LDS, 16B per lane; LDS dest is wave-uniform base + lane*16
#define GLOAD_LDS16(g, l)                                                  \
  __builtin_amdgcn_global_load_lds(                                       \
      (const __attribute__((address_space(1))) unsigned int*)(g),         \
      (__attribute__((address_space(3))) unsigned int*)(l), 16, 0, 0)

// v_cvt_pk_bf16_f32: d.lo16 = bf16_rne(lo), d.hi16 = bf16_rne(hi). 1 VALU op
// for 2 conversions vs 4 integer ops/value for the manual RNE sequence.
__device__ __forceinline__ unsigned cvt_pk_bf16(float lo, float hi) {
  unsigned d;
  asm("v_cvt_pk_bf16_f32 %0, %1, %2" : "=v"(d) : "v"(lo), "v"(hi));
  return d;
}

__device__ __forceinline__ unsigned short f2bf(float f) {
  union { float f; unsigned u; } v; v.f = f;
  unsigned r = v.u + 0x7fffu + ((v.u >> 16) & 1u);
  return (unsigned short)(r >> 16);
}

// Convert 8 fp32 -> bf16x8 via 4x v_cvt_pk_bf16_f32 (was 32 integer ops).
__device__ __forceinline__ short8 cvt8(f4 a, f4 b) {
  union { unsigned u[4]; short8 s; } r;
  r.u[0] = cvt_pk_bf16(a[0], a[1]);
  r.u[1] = cvt_pk_bf16(a[2], a[3]);
  r.u[2] = cvt_pk_bf16(b[0], b[1]);
  r.u[3] = cvt_pk_bf16(b[2], b[3]);
  return r.s;
}

// ---------------------------------------------------------------------------
// QKV projection. Y = X W^T + b (fp32 in, bf16 out). Tile 128x128, BK=32.
// Q,K dst: [NH][L][64]. V dst: [NH][64][L] transposed AND key-permuted within
// 32-blocks (pos = ((k&15)>>2)*8 + ((k>>4)&1)*4 + (k&3)) so attn's b128
// V-fragments feed K=32 PV MFMAs whose B operand is P in registers.
// R5 change: DOUBLE-BUFFERED a/b LDS -> ONE barrier per K-step (was 2).
// Hazard proof: write(buf b)@step k+2 occurs after barrier(k+1); every
// wave's LDS reads of buf b @step k are consumed (lgkmcnt-waited by its
// MFMAs) before it enters barrier(k+1). c_lds is disjoint memory.
// ---------------------------------------------------------------------------
__global__ __launch_bounds__(256, 2) void proj_gemm(
    const float* __restrict__ Xq, const float* __restrict__ Xk,
    const float* __restrict__ Xv,
    const float* __restrict__ Wq, const float* __restrict__ Wk,
    const float* __restrict__ Wv,
    const float* __restrict__ bq, const float* __restrict__ bk,
    const float* __restrict__ bv,
    unsigned short* __restrict__ dst_base)
{
  __shared__ __align__(16) unsigned short a_lds[2][128 * 32];
  __shared__ __align__(16) unsigned short b_lds[2][128 * 32];
  __shared__ __align__(16) unsigned short c_lds[64 * 136];

  const int id = blockIdx.x;                 // 0..575
  const int xcd = id & 7, local = id >> 3;
  const int grp = local / 6, bnIdx = local % 6;
  const int G = grp * 8 + xcd;               // 0..95 bijective
  const int z = G >> 5;
  const int bm = (G & 31) * 128, bn = bnIdx * 128;

  const float* X = (z == 0) ? Xq : ((z == 1) ? Xk : Xv);
  const float* W = (z == 0) ? Wq : ((z == 1) ? Wk : Wv);
  const float* bias = (z == 0) ? bq : ((z == 1) ? bk : bv);
  unsigned short* dst = dst_base + (size_t)z * NHEAD * LSEQ * 64;

  const int tid = threadIdx.x;
  const int wave = tid >> 6, lane = tid & 63;
  const int quad = lane >> 4, l16 = lane & 15;
  const int wm = (wave >> 1) * 64, wn = (wave & 1) * 64;

  v4f acc[4][4];
  for (int i = 0; i < 4; ++i)
    for (int j = 0; j < 4; ++j)
      acc[i][j] = (v4f){0.f, 0.f, 0.f, 0.f};

  const int row_s = tid >> 2;
  const int c8_s = (tid & 3) * 8;

  const float* xrow[2]; const float* wrow[2];
#pragma unroll
  for (int s = 0; s < 2; ++s) {
    xrow[s] = X + (size_t)(bm + row_s + 64 * s) * HDIM + c8_s;
    wrow[s] = W + (size_t)(bn + row_s + 64 * s) * HDIM + c8_s;
  }

  f4 pa[2][2], pw[2][2];
#pragma unroll
  for (int s = 0; s < 2; ++s) {
    pa[s][0] = *(const f4*)(xrow[s]);     pa[s][1] = *(const f4*)(xrow[s] + 4);
    pw[s][0] = *(const f4*)(wrow[s]);     pw[s][1] = *(const f4*)(wrow[s] + 4);
  }

  for (int k0 = 0; k0 < HDIM; k0 += 32) {
    const int cur = (k0 >> 5) & 1;
    // stage current tile from regs into buffer `cur` (read @ k0-64 is long done)
#pragma unroll
    for (int s = 0; s < 2; ++s) {
      *(short8*)&a_lds[cur][(row_s + 64 * s) * 32 + c8_s] = cvt8(pa[s][0], pa[s][1]);
      *(short8*)&b_lds[cur][(row_s + 64 * s) * 32 + c8_s] = cvt8(pw[s][0], pw[s][1]);
    }
    __syncthreads();   // single barrier per K-step

    if (k0 + 32 < HDIM) {
#pragma unroll
      for (int s = 0; s < 2; ++s) {
        pa[s][0] = *(const f4*)(xrow[s] + k0 + 32);
        pa[s][1] = *(const f4*)(xrow[s] + k0 + 36);
        pw[s][0] = *(const f4*)(wrow[s] + k0 + 32);
        pw[s][1] = *(const f4*)(wrow[s] + k0 + 36);
      }
    }

    short8 af[4], bfr[4];
    for (int i = 0; i < 4; ++i)
      af[i] = *(const short8*)&a_lds[cur][(wm + i * 16 + l16) * 32 + quad * 8];
    for (int j = 0; j < 4; ++j)
      bfr[j] = *(const short8*)&b_lds[cur][(wn + j * 16 + l16) * 32 + quad * 8];
    if (z == 2) {
      for (int i = 0; i < 4; ++i)
        for (int j = 0; j < 4; ++j)
          acc[i][j] = __builtin_amdgcn_mfma_f32_16x16x32_bf16(bfr[j], af[i], acc[i][j], 0, 0, 0);
    } else {
      for (int i = 0; i < 4; ++i)
        for (int j = 0; j < 4; ++j)
          acc[i][j] = __builtin_amdgcn_mfma_f32_16x16x32_bf16(af[i], bfr[j], acc[i][j], 0, 0, 0);
    }
  }

  for (int p = 0; p < 2; ++p) {
    __syncthreads();
    if (z == 2) {
      if ((wave & 1) == p) {
        // C^T: row = d-local, col = seq-local. Apply the key permutation
        // within 32-blocks while writing c_lds: s = (i&1)*16 + l16 ->
        // s' = (l16>>2)*8 + (i&1)*4 + (l16&3).
        for (int j = 0; j < 4; ++j)
          for (int r = 0; r < 4; ++r) {
            float bvv = bias[bn + wn + j * 16 + quad * 4 + r];
            int row = j * 16 + quad * 4 + r;
            for (int i = 0; i < 4; ++i) {
              int colp = wm + (i >> 1) * 32 + (l16 >> 2) * 8 + (i & 1) * 4 + (l16 & 3);
              c_lds[row * 136 + colp] = f2bf(acc[i][j][r] + bvv);
            }
          }
      }
    } else {
      if ((wave >> 1) == p) {
        for (int j = 0; j < 4; ++j) {
          float bvv = bias[bn + wn + j * 16 + l16];
          for (int i = 0; i < 4; ++i)
            for (int r = 0; r < 4; ++r)
              c_lds[(i * 16 + quad * 4 + r) * 136 + wn + j * 16 + l16] =
                  f2bf(acc[i][j][r] + bvv);
        }
      }
    }
    __syncthreads();
    int row = tid >> 2, c = tid & 3;
    const unsigned short* srow = &c_lds[row * 136 + c * 32];
    if (z == 2) {
      int n = bn + p * 64 + row;
      int hh = n >> 6, d = n & 63;
      unsigned short* drow = dst + ((size_t)hh * 64 + d) * LSEQ + bm + c * 32;
      for (int q8 = 0; q8 < 4; ++q8)
        *(u32x4*)(drow + q8 * 8) = *(const u32x4*)(srow + q8 * 8);
    } else {
      int m = bm + p * 64 + row;
      int nbase = bn + c * 32;
      int hh = nbase >> 6, d = nbase & 63;
      unsigned short* drow = dst + ((size_t)hh * LSEQ + m) * 64 + d;
      for (int q8 = 0; q8 < 4; ++q8)
        *(u32x4*)(drow + q8 * 8) = *(const u32x4*)(srow + q8 * 8);
    }
  }
}

// ---------------------------------------------------------------------------
// Flash attention — BYTE-EXACT revert to the verified R1 kernel (78.6 us,
// absmax 2.44e-4). S^T formulation: mfma(kf,qf) -> S^T whose C-layout IS the
// B-operand layout for PV (P never round-trips LDS). PV = mfma(V^T-frag,
// P-regs) -> O^T. V key-permuted in ws so b128 frags feed K=32 MFMA.
// 4 waves = (q-half qg x key-half kh); no-max softmax; double-buffered async
// staging, one barrier/tile; denominator on the matrix pipe (ones-MFMA).
// grid = (64, 12), block = 256.
// ---------------------------------------------------------------------------
__global__ __launch_bounds__(256, 3) void attn(
    const unsigned short* __restrict__ Q, const unsigned short* __restrict__ K,
    const unsigned short* __restrict__ Vt, const float* __restrict__ mask,
    float* __restrict__ out)
{
  __shared__ __align__(16) unsigned short smem[4 * 64 * 64];  // 32 KB
  // k buf b: smem + b*4096 ; vt buf b: smem + 8192 + b*4096   (shorts)

  const int h = blockIdx.y;
  const int qt = blockIdx.x;
  const int tid = threadIdx.x;
  const int wave = tid >> 6, lane = tid & 63;
  const int quad = lane >> 4, l16 = lane & 15;
  const int qg = wave & 1, kh = wave >> 1;

  const unsigned short* Qh  = Q  + (size_t)h * LSEQ * 64;
  const unsigned short* Kh  = K  + (size_t)h * LSEQ * 64;
  const unsigned short* Vth = Vt + (size_t)h * 64 * LSEQ;

  // Async staging: wave stages segs wave*2+s (1 KB each) of both
  // K [key][d] (chunk^(key&7)) and V^T [d][key] (chunk^(d&7)).
  const unsigned short* ksrc[2]; const unsigned short* vsrc[2];
  unsigned short* kdst[2]; unsigned short* vdst[2];
#pragma unroll
  for (int s = 0; s < 2; ++s) {
    int seg = wave * 2 + s;
    int rl = lane >> 3, cc = (lane & 7) ^ rl;
    ksrc[s] = Kh + (size_t)(seg * 8 + rl) * 64 + cc * 8;
    vsrc[s] = Vth + (size_t)(seg * 8 + rl) * LSEQ + cc * 8;
    kdst[s] = smem + seg * 512;
    vdst[s] = smem + 8192 + seg * 512;
  }

  // Q fragments (B-operand for QK): 32 q-rows (qg half), both d-chunks.
  short8 qf[2][2];
#pragma unroll
  for (int qi = 0; qi < 2; ++qi)
#pragma unroll
    for (int c = 0; c < 2; ++c)
      qf[qi][c] = *(const short8*)(Qh + (size_t)(qt * 64 + qg * 32 + qi * 16 + l16) * 64 +
                                   c * 32 + quad * 8);

  // ones fragment (bf16 1.0) for the denominator MFMA
  short8 ones8;
#pragma unroll
  for (int i = 0; i < 8; ++i) ones8[i] = (short)0x3F80;

  v4f acc[2][4];   // O^T: [qi][d-tile j], C-layout col=q(l16), row=d(quad*4+r)
  v4f lacc[2];     // denominator: D[row][q] = sum_k P[k][q] (rows all equal)
#pragma unroll
  for (int qi = 0; qi < 2; ++qi) {
    for (int j = 0; j < 4; ++j) acc[qi][j] = (v4f){0.f, 0.f, 0.f, 0.f};
    lacc[qi] = (v4f){0.f, 0.f, 0.f, 0.f};
  }

  // prologue: tile 0 into buf 0
#pragma unroll
  for (int s = 0; s < 2; ++s) { GLOAD_LDS16(ksrc[s], kdst[s]); GLOAD_LDS16(vsrc[s], vdst[s]); }

#pragma unroll 2
  for (int kt = 0; kt < 64; ++kt) {
    const int key0 = kt * 64;
    const int buf = kt & 1, nbuf = (kt + 1) & 1;

    __syncthreads();  // own-wave vmcnt(0) drain + all waves done with buf[nbuf]

    if (kt < 63) {
      size_t ko = (size_t)(key0 + 64) * 64;
#pragma unroll
      for (int s = 0; s < 2; ++s) {
        GLOAD_LDS16(ksrc[s] + ko, kdst[s] + nbuf * 4096);
        GLOAD_LDS16(vsrc[s] + (key0 + 64), vdst[s] + nbuf * 4096);
      }
    }

    // mask per key (additive, broadcast over q): lane's keys = quad*4+r
    f4 mvs[2];
#pragma unroll
    for (int k2 = 0; k2 < 2; ++k2)
      mvs[k2] = *(const f4*)(mask + key0 + kh * 32 + k2 * 16 + quad * 4) * 1.44269504f;

    // K fragments (A-operand): row = key, 4 reads hoisted over qi
    const unsigned short* kb = smem + buf * 4096;
    short8 kf[2][2];
#pragma unroll
    for (int k2 = 0; k2 < 2; ++k2)
#pragma unroll
      for (int c = 0; c < 2; ++c) {
        int row = kh * 32 + k2 * 16 + l16;
        kf[k2][c] = *(const short8*)&kb[row * 64 + (((c * 4 + quad) ^ (row & 7)) << 3)];
      }

    // S^T = K Q^T : 8 MFMA; lane holds key=quad*4+r, q=l16
    v4f sacc[2][2];
#pragma unroll
    for (int k2 = 0; k2 < 2; ++k2)
      for (int qi = 0; qi < 2; ++qi) sacc[k2][qi] = (v4f){0.f, 0.f, 0.f, 0.f};
#pragma unroll
    for (int c = 0; c < 2; ++c)
#pragma unroll
      for (int k2 = 0; k2 < 2; ++k2)
#pragma unroll
        for (int qi = 0; qi < 2; ++qi)
          sacc[k2][qi] = __builtin_amdgcn_mfma_f32_16x16x32_bf16(
              kf[k2][c], qf[qi][c], sacc[k2][qi], 0, 0, 0);

    // exp -> pack into PV B-operand registers via v_cvt_pk_bf16_f32 (RNE)
    union { unsigned u[4]; short8 s8; } pb[2];
#pragma unroll
    for (int qi = 0; qi < 2; ++qi)
#pragma unroll
      for (int k2 = 0; k2 < 2; ++k2) {
        float e[4];
#pragma unroll
        for (int r = 0; r < 4; ++r)
          e[r] = EXP2F(fmaf(sacc[k2][qi][r], 0.18033688f, mvs[k2][r]));
        pb[qi].u[k2 * 2 + 0] = cvt_pk_bf16(e[0], e[1]);
        pb[qi].u[k2 * 2 + 1] = cvt_pk_bf16(e[2], e[3]);
      }

    // denominator on the matrix pipe: lacc += ones(16x32) @ P(32x16).
    // Sums the ROUNDED bf16 P (same values PV uses) -> bias cancels in the
    // final normalization exactly as the old truncate-consistent scheme.
#pragma unroll
    for (int qi = 0; qi < 2; ++qi)
      lacc[qi] = __builtin_amdgcn_mfma_f32_16x16x32_bf16(
          ones8, pb[qi].s8, lacc[qi], 0, 0, 0);

    // V^T fragments (A-operand; key-permuted in ws): 4 reads hoisted over qi
    const unsigned short* vb = smem + 8192 + buf * 4096;
    short8 vf[4];
#pragma unroll
    for (int j = 0; j < 4; ++j) {
      int d = j * 16 + l16;
      vf[j] = *(const short8*)&vb[d * 64 + (((kh * 4 + quad) ^ (d & 7)) << 3)];
    }

    // O^T += V^T P^T : 8 MFMA
#pragma unroll
    for (int qi = 0; qi < 2; ++qi)
#pragma unroll
      for (int j = 0; j < 4; ++j)
        acc[qi][j] = __builtin_amdgcn_mfma_f32_16x16x32_bf16(
            vf[j], pb[qi].s8, acc[qi][j], 0, 0, 0);
  }

  // denominator is fully reduced over k by the ones-MFMA: all rows/quads
  // already hold the same per-q sum -> no shuffles needed.
  float lsum[2] = { lacc[0][0], lacc[1][0] };

  // merge key-halves (reuse staging LDS; stride 66 floats -> conflict-light)
  __syncthreads();
  float* mrg = (float*)smem;                 // 64 rows x 66 floats
  float* lsl = mrg + 64 * 66;                // 64 floats
  if (kh == 1) {
#pragma unroll
    for (int qi = 0; qi < 2; ++qi) {
      int qrow = (qg * 2 + qi) * 16 + l16;
#pragma unroll
      for (int j = 0; j < 4; ++j)
#pragma unroll
        for (int r = 0; r < 4; ++r)
          mrg[qrow * 66 + j * 16 + quad * 4 + r] = acc[qi][j][r];
      if (quad == 0) lsl[qrow] = lsum[qi];
    }
  }
  __syncthreads();
  if (kh == 0) {
#pragma unroll
    for (int qi = 0; qi < 2; ++qi) {
      int qrow = (qg * 2 + qi) * 16 + l16;
      float inv = 1.0f / (lsum[qi] + lsl[qrow]);
      int row = qt * 64 + qg * 32 + qi * 16 + l16;
#pragma unroll
      for (int j = 0; j < 4; ++j) {
        f4 o;
#pragma unroll
        for (int r = 0; r < 4; ++r)
          o[r] = (acc[qi][j][r] + mrg[qrow * 66 + j * 16 + quad * 4 + r]) * inv;
        *(f4*)(out + (size_t)row * HDIM + h * 64 + j * 16 + quad * 4) = o;
      }
    }
  }
}

extern "C" void kernel_launch(void* const* d_in, const int* in_sizes, int n_in,
                              void* d_out, int out_size, void* d_ws, size_t ws_size,
                              hipStream_t stream) {
  const float* query = (const float*)d_in[0];
  const float* key   = (const float*)d_in[1];
  const float* value = (const float*)d_in[2];
  const float* mask  = (const float*)d_in[3];
  const float* Wq = (const float*)d_in[4];
  const float* bq = (const float*)d_in[5];
  const float* Wk = (const float*)d_in[6];
  const float* bk = (const float*)d_in[7];
  const float* Wv = (const float*)d_in[8];
  const float* bv = (const float*)d_in[9];
  float* out = (float*)d_out;

  // ws usage: exactly 3 * NHEAD*LSEQ*64 bf16 = 18,874,368 bytes (hard limit —
  // writing 4 bytes past this corrupted a pristine input copy in round 2).
  unsigned short* Qb = (unsigned short*)d_ws;                  // [NH][L][64] bf16
  unsigned short* Kb = Qb + (size_t)NHEAD * LSEQ * 64;         // [NH][L][64] bf16
  unsigned short* Vb = Kb + (size_t)NHEAD * LSEQ * 64;         // [NH][64][L] bf16, key-permuted

  proj_gemm<<<576, 256, 0, stream>>>(
      query, key, value, Wq, Wk, Wv, bq, bk, bv, Qb);
  attn<<<dim3(LSEQ / 64, NHEAD), 256, 0, stream>>>(Qb, Kb, Vb, mask, out);
}

// Round 6
// 198.653 us; speedup vs baseline: 1.0995x; 1.0330x over previous
//
#include <hip/hip_runtime.h>
#include <math.h>

#define LSEQ 4096
#define HDIM 768
#define NHEAD 12

using v4f    = __attribute__((ext_vector_type(4))) float;
using f4     = __attribute__((ext_vector_type(4))) float;
using short8 = __attribute__((ext_vector_type(8))) short;
using u32x4  = __attribute__((ext_vector_type(4))) unsigned int;

#if __has_builtin(__builtin_amdgcn_exp2f)
#define EXP2F(x) __builtin_amdgcn_exp2f(x)
#else
#define EXP2F(x) exp2f(x)
#endif

// async global->LDS, 16B per lane; LDS dest is wave-uniform base + lane*16
#define GLOAD_LDS16(g, l)                                                  \
  __builtin_amdgcn_global_load_lds(                                       \
      (const __attribute__((address_space(1))) unsigned int*)(g),         \
      (__attribute__((address_space(3))) unsigned int*)(l), 16, 0, 0)

// v_cvt_pk_bf16_f32: d.lo16 = bf16_rne(lo), d.hi16 = bf16_rne(hi). 1 VALU op
// for 2 conversions vs 4 integer ops/value for the manual RNE sequence.
__device__ __forceinline__ unsigned cvt_pk_bf16(float lo, float hi) {
  unsigned d;
  asm("v_cvt_pk_bf16_f32 %0, %1, %2" : "=v"(d) : "v"(lo), "v"(hi));
  return d;
}

__device__ __forceinline__ unsigned short f2bf(float f) {
  union { float f; unsigned u; } v; v.f = f;
  unsigned r = v.u + 0x7fffu + ((v.u >> 16) & 1u);
  return (unsigned short)(r >> 16);
}

// Convert 8 fp32 -> bf16x8 via 4x v_cvt_pk_bf16_f32 (was 32 integer ops).
__device__ __forceinline__ short8 cvt8(f4 a, f4 b) {
  union { unsigned u[4]; short8 s; } r;
  r.u[0] = cvt_pk_bf16(a[0], a[1]);
  r.u[1] = cvt_pk_bf16(a[2], a[3]);
  r.u[2] = cvt_pk_bf16(b[0], b[1]);
  r.u[3] = cvt_pk_bf16(b[2], b[3]);
  return r.s;
}

// ---------------------------------------------------------------------------
// QKV projection. Y = X W^T + b (fp32 in, bf16 out). Tile 128x128, BK=32.
// Q,K dst: [NH][L][64]. V dst: [NH][64][L] transposed AND key-permuted within
// 32-blocks (pos = ((k&15)>>2)*8 + ((k>>4)&1)*4 + (k&3)) so attn's b128
// V-fragments feed K=32 PV MFMAs whose B operand is P in registers.
// Double-buffered a/b LDS -> one barrier per K-step (verified R5).
// ---------------------------------------------------------------------------
__global__ __launch_bounds__(256, 2) void proj_gemm(
    const float* __restrict__ Xq, const float* __restrict__ Xk,
    const float* __restrict__ Xv,
    const float* __restrict__ Wq, const float* __restrict__ Wk,
    const float* __restrict__ Wv,
    const float* __restrict__ bq, const float* __restrict__ bk,
    const float* __restrict__ bv,
    unsigned short* __restrict__ dst_base)
{
  __shared__ __align__(16) unsigned short a_lds[2][128 * 32];
  __shared__ __align__(16) unsigned short b_lds[2][128 * 32];
  __shared__ __align__(16) unsigned short c_lds[64 * 136];

  const int id = blockIdx.x;                 // 0..575
  const int xcd = id & 7, local = id >> 3;
  const int grp = local / 6, bnIdx = local % 6;
  const int G = grp * 8 + xcd;               // 0..95 bijective
  const int z = G >> 5;
  const int bm = (G & 31) * 128, bn = bnIdx * 128;

  const float* X = (z == 0) ? Xq : ((z == 1) ? Xk : Xv);
  const float* W = (z == 0) ? Wq : ((z == 1) ? Wk : Wv);
  const float* bias = (z == 0) ? bq : ((z == 1) ? bk : bv);
  unsigned short* dst = dst_base + (size_t)z * NHEAD * LSEQ * 64;

  const int tid = threadIdx.x;
  const int wave = tid >> 6, lane = tid & 63;
  const int quad = lane >> 4, l16 = lane & 15;
  const int wm = (wave >> 1) * 64, wn = (wave & 1) * 64;

  v4f acc[4][4];
  for (int i = 0; i < 4; ++i)
    for (int j = 0; j < 4; ++j)
      acc[i][j] = (v4f){0.f, 0.f, 0.f, 0.f};

  const int row_s = tid >> 2;
  const int c8_s = (tid & 3) * 8;

  const float* xrow[2]; const float* wrow[2];
#pragma unroll
  for (int s = 0; s < 2; ++s) {
    xrow[s] = X + (size_t)(bm + row_s + 64 * s) * HDIM + c8_s;
    wrow[s] = W + (size_t)(bn + row_s + 64 * s) * HDIM + c8_s;
  }

  f4 pa[2][2], pw[2][2];
#pragma unroll
  for (int s = 0; s < 2; ++s) {
    pa[s][0] = *(const f4*)(xrow[s]);     pa[s][1] = *(const f4*)(xrow[s] + 4);
    pw[s][0] = *(const f4*)(wrow[s]);     pw[s][1] = *(const f4*)(wrow[s] + 4);
  }

  for (int k0 = 0; k0 < HDIM; k0 += 32) {
    const int cur = (k0 >> 5) & 1;
    // stage current tile from regs into buffer `cur` (read @ k0-64 is long done)
#pragma unroll
    for (int s = 0; s < 2; ++s) {
      *(short8*)&a_lds[cur][(row_s + 64 * s) * 32 + c8_s] = cvt8(pa[s][0], pa[s][1]);
      *(short8*)&b_lds[cur][(row_s + 64 * s) * 32 + c8_s] = cvt8(pw[s][0], pw[s][1]);
    }
    __syncthreads();   // single barrier per K-step

    if (k0 + 32 < HDIM) {
#pragma unroll
      for (int s = 0; s < 2; ++s) {
        pa[s][0] = *(const f4*)(xrow[s] + k0 + 32);
        pa[s][1] = *(const f4*)(xrow[s] + k0 + 36);
        pw[s][0] = *(const f4*)(wrow[s] + k0 + 32);
        pw[s][1] = *(const f4*)(wrow[s] + k0 + 36);
      }
    }

    short8 af[4], bfr[4];
    for (int i = 0; i < 4; ++i)
      af[i] = *(const short8*)&a_lds[cur][(wm + i * 16 + l16) * 32 + quad * 8];
    for (int j = 0; j < 4; ++j)
      bfr[j] = *(const short8*)&b_lds[cur][(wn + j * 16 + l16) * 32 + quad * 8];
    if (z == 2) {
      for (int i = 0; i < 4; ++i)
        for (int j = 0; j < 4; ++j)
          acc[i][j] = __builtin_amdgcn_mfma_f32_16x16x32_bf16(bfr[j], af[i], acc[i][j], 0, 0, 0);
    } else {
      for (int i = 0; i < 4; ++i)
        for (int j = 0; j < 4; ++j)
          acc[i][j] = __builtin_amdgcn_mfma_f32_16x16x32_bf16(af[i], bfr[j], acc[i][j], 0, 0, 0);
    }
  }

  for (int p = 0; p < 2; ++p) {
    __syncthreads();
    if (z == 2) {
      if ((wave & 1) == p) {
        // C^T: row = d-local, col = seq-local. Apply the key permutation
        // within 32-blocks while writing c_lds: s = (i&1)*16 + l16 ->
        // s' = (l16>>2)*8 + (i&1)*4 + (l16&3).
        for (int j = 0; j < 4; ++j)
          for (int r = 0; r < 4; ++r) {
            float bvv = bias[bn + wn + j * 16 + quad * 4 + r];
            int row = j * 16 + quad * 4 + r;
            for (int i = 0; i < 4; ++i) {
              int colp = wm + (i >> 1) * 32 + (l16 >> 2) * 8 + (i & 1) * 4 + (l16 & 3);
              c_lds[row * 136 + colp] = f2bf(acc[i][j][r] + bvv);
            }
          }
      }
    } else {
      if ((wave >> 1) == p) {
        for (int j = 0; j < 4; ++j) {
          float bvv = bias[bn + wn + j * 16 + l16];
          for (int i = 0; i < 4; ++i)
            for (int r = 0; r < 4; ++r)
              c_lds[(i * 16 + quad * 4 + r) * 136 + wn + j * 16 + l16] =
                  f2bf(acc[i][j][r] + bvv);
        }
      }
    }
    __syncthreads();
    int row = tid >> 2, c = tid & 3;
    const unsigned short* srow = &c_lds[row * 136 + c * 32];
    if (z == 2) {
      int n = bn + p * 64 + row;
      int hh = n >> 6, d = n & 63;
      unsigned short* drow = dst + ((size_t)hh * 64 + d) * LSEQ + bm + c * 32;
      for (int q8 = 0; q8 < 4; ++q8)
        *(u32x4*)(drow + q8 * 8) = *(const u32x4*)(srow + q8 * 8);
    } else {
      int m = bm + p * 64 + row;
      int nbase = bn + c * 32;
      int hh = nbase >> 6, d = nbase & 63;
      unsigned short* drow = dst + ((size_t)hh * LSEQ + m) * 64 + d;
      for (int q8 = 0; q8 < 4; ++q8)
        *(u32x4*)(drow + q8 * 8) = *(const u32x4*)(srow + q8 * 8);
    }
  }
}

// ---------------------------------------------------------------------------
// Flash attention (verified R1/R5 structure). S^T formulation: mfma(kf,qf) ->
// S^T whose C-layout IS the B-operand layout for PV. PV = mfma(V^T-frag,
// P-regs) -> O^T. 4 waves = (q-half qg x key-half kh); no-max softmax;
// double-buffered async staging, one barrier/tile; denominator via ones-MFMA.
// R6 change: MASK STAGED TO LDS (prescaled by log2e). Before, the per-tile
// mask loads were global dwordx4 in the same vmcnt domain as the async
// global_load_lds prefetches; in-order vmcnt completion meant consuming mvs
// could drain the prefetches mid-body (defeating the async pipeline). With
// mask in LDS, the loop's ONLY vmem ops are the 4 prefetches, which stay in
// flight until the pre-barrier vmcnt(0). LDS 32->48 KB: residency still 3
// blocks/CU (grid-limited), so no occupancy cost.
// grid = (64, 12), block = 256.
// ---------------------------------------------------------------------------
__global__ __launch_bounds__(256, 3) void attn(
    const unsigned short* __restrict__ Q, const unsigned short* __restrict__ K,
    const unsigned short* __restrict__ Vt, const float* __restrict__ mask,
    float* __restrict__ out)
{
  __shared__ __align__(16) unsigned short smem[4 * 64 * 64];  // 32 KB
  __shared__ __align__(16) float mask_lds[LSEQ];              // 16 KB, prescaled
  // k buf b: smem + b*4096 ; vt buf b: smem + 8192 + b*4096   (shorts)

  const int h = blockIdx.y;
  const int qt = blockIdx.x;
  const int tid = threadIdx.x;
  const int wave = tid >> 6, lane = tid & 63;
  const int quad = lane >> 4, l16 = lane & 15;
  const int qg = wave & 1, kh = wave >> 1;

  const unsigned short* Qh  = Q  + (size_t)h * LSEQ * 64;
  const unsigned short* Kh  = K  + (size_t)h * LSEQ * 64;
  const unsigned short* Vth = Vt + (size_t)h * 64 * LSEQ;

  // stage mask -> LDS once, prescaled by log2(e) (same fp32 rounding as the
  // old per-tile mv * 1.44269504f).
#pragma unroll
  for (int i = 0; i < LSEQ / 4 / 256; ++i) {
    int idx = (i * 256 + tid) * 4;
    f4 m = *(const f4*)(mask + idx);
    *(f4*)&mask_lds[idx] = m * 1.44269504f;
  }

  // Async staging: wave stages segs wave*2+s (1 KB each) of both
  // K [key][d] (chunk^(key&7)) and V^T [d][key] (chunk^(d&7)).
  const unsigned short* ksrc[2]; const unsigned short* vsrc[2];
  unsigned short* kdst[2]; unsigned short* vdst[2];
#pragma unroll
  for (int s = 0; s < 2; ++s) {
    int seg = wave * 2 + s;
    int rl = lane >> 3, cc = (lane & 7) ^ rl;
    ksrc[s] = Kh + (size_t)(seg * 8 + rl) * 64 + cc * 8;
    vsrc[s] = Vth + (size_t)(seg * 8 + rl) * LSEQ + cc * 8;
    kdst[s] = smem + seg * 512;
    vdst[s] = smem + 8192 + seg * 512;
  }

  // Q fragments (B-operand for QK): 32 q-rows (qg half), both d-chunks.
  short8 qf[2][2];
#pragma unroll
  for (int qi = 0; qi < 2; ++qi)
#pragma unroll
    for (int c = 0; c < 2; ++c)
      qf[qi][c] = *(const short8*)(Qh + (size_t)(qt * 64 + qg * 32 + qi * 16 + l16) * 64 +
                                   c * 32 + quad * 8);

  // ones fragment (bf16 1.0) for the denominator MFMA
  short8 ones8;
#pragma unroll
  for (int i = 0; i < 8; ++i) ones8[i] = (short)0x3F80;

  v4f acc[2][4];   // O^T: [qi][d-tile j], C-layout col=q(l16), row=d(quad*4+r)
  v4f lacc[2];     // denominator: D[row][q] = sum_k P[k][q] (rows all equal)
#pragma unroll
  for (int qi = 0; qi < 2; ++qi) {
    for (int j = 0; j < 4; ++j) acc[qi][j] = (v4f){0.f, 0.f, 0.f, 0.f};
    lacc[qi] = (v4f){0.f, 0.f, 0.f, 0.f};
  }

  // prologue: tile 0 into buf 0
#pragma unroll
  for (int s = 0; s < 2; ++s) { GLOAD_LDS16(ksrc[s], kdst[s]); GLOAD_LDS16(vsrc[s], vdst[s]); }

#pragma unroll 2
  for (int kt = 0; kt < 64; ++kt) {
    const int key0 = kt * 64;
    const int buf = kt & 1, nbuf = (kt + 1) & 1;

    __syncthreads();  // own-wave vmcnt(0) drain + all waves done with buf[nbuf]
                      // (kt=0: also covers mask_lds ds_writes via lgkmcnt(0))

    if (kt < 63) {
      size_t ko = (size_t)(key0 + 64) * 64;
#pragma unroll
      for (int s = 0; s < 2; ++s) {
        GLOAD_LDS16(ksrc[s] + ko, kdst[s] + nbuf * 4096);
        GLOAD_LDS16(vsrc[s] + (key0 + 64), vdst[s] + nbuf * 4096);
      }
    }

    // mask per key (prescaled, from LDS -> lgkmcnt domain, no vmcnt coupling)
    f4 mvs[2];
#pragma unroll
    for (int k2 = 0; k2 < 2; ++k2)
      mvs[k2] = *(const f4*)&mask_lds[key0 + kh * 32 + k2 * 16 + quad * 4];

    // K fragments (A-operand): row = key, 4 reads hoisted over qi
    const unsigned short* kb = smem + buf * 4096;
    short8 kf[2][2];
#pragma unroll
    for (int k2 = 0; k2 < 2; ++k2)
#pragma unroll
      for (int c = 0; c < 2; ++c) {
        int row = kh * 32 + k2 * 16 + l16;
        kf[k2][c] = *(const short8*)&kb[row * 64 + (((c * 4 + quad) ^ (row & 7)) << 3)];
      }

    // S^T = K Q^T : 8 MFMA; lane holds key=quad*4+r, q=l16
    v4f sacc[2][2];
#pragma unroll
    for (int k2 = 0; k2 < 2; ++k2)
      for (int qi = 0; qi < 2; ++qi) sacc[k2][qi] = (v4f){0.f, 0.f, 0.f, 0.f};
#pragma unroll
    for (int c = 0; c < 2; ++c)
#pragma unroll
      for (int k2 = 0; k2 < 2; ++k2)
#pragma unroll
        for (int qi = 0; qi < 2; ++qi)
          sacc[k2][qi] = __builtin_amdgcn_mfma_f32_16x16x32_bf16(
              kf[k2][c], qf[qi][c], sacc[k2][qi], 0, 0, 0);

    // exp -> pack into PV B-operand registers via v_cvt_pk_bf16_f32 (RNE)
    union { unsigned u[4]; short8 s8; } pb[2];
#pragma unroll
    for (int qi = 0; qi < 2; ++qi)
#pragma unroll
      for (int k2 = 0; k2 < 2; ++k2) {
        float e[4];
#pragma unroll
        for (int r = 0; r < 4; ++r)
          e[r] = EXP2F(fmaf(sacc[k2][qi][r], 0.18033688f, mvs[k2][r]));
        pb[qi].u[k2 * 2 + 0] = cvt_pk_bf16(e[0], e[1]);
        pb[qi].u[k2 * 2 + 1] = cvt_pk_bf16(e[2], e[3]);
      }

    // denominator on the matrix pipe: lacc += ones(16x32) @ P(32x16).
    // Sums the ROUNDED bf16 P (same values PV uses) -> bias cancels in the
    // final normalization exactly as the old truncate-consistent scheme.
#pragma unroll
    for (int qi = 0; qi < 2; ++qi)
      lacc[qi] = __builtin_amdgcn_mfma_f32_16x16x32_bf16(
          ones8, pb[qi].s8, lacc[qi], 0, 0, 0);

    // V^T fragments (A-operand; key-permuted in ws): 4 reads hoisted over qi
    const unsigned short* vb = smem + 8192 + buf * 4096;
    short8 vf[4];
#pragma unroll
    for (int j = 0; j < 4; ++j) {
      int d = j * 16 + l16;
      vf[j] = *(const short8*)&vb[d * 64 + (((kh * 4 + quad) ^ (d & 7)) << 3)];
    }

    // O^T += V^T P^T : 8 MFMA
#pragma unroll
    for (int qi = 0; qi < 2; ++qi)
#pragma unroll
      for (int j = 0; j < 4; ++j)
        acc[qi][j] = __builtin_amdgcn_mfma_f32_16x16x32_bf16(
            vf[j], pb[qi].s8, acc[qi][j], 0, 0, 0);
  }

  // denominator is fully reduced over k by the ones-MFMA: all rows/quads
  // already hold the same per-q sum -> no shuffles needed.
  float lsum[2] = { lacc[0][0], lacc[1][0] };

  // merge key-halves (reuse staging LDS; stride 66 floats -> conflict-light)
  __syncthreads();
  float* mrg = (float*)smem;                 // 64 rows x 66 floats
  float* lsl = mrg + 64 * 66;                // 64 floats
  if (kh == 1) {
#pragma unroll
    for (int qi = 0; qi < 2; ++qi) {
      int qrow = (qg * 2 + qi) * 16 + l16;
#pragma unroll
      for (int j = 0; j < 4; ++j)
#pragma unroll
        for (int r = 0; r < 4; ++r)
          mrg[qrow * 66 + j * 16 + quad * 4 + r] = acc[qi][j][r];
      if (quad == 0) lsl[qrow] = lsum[qi];
    }
  }
  __syncthreads();
  if (kh == 0) {
#pragma unroll
    for (int qi = 0; qi < 2; ++qi) {
      int qrow = (qg * 2 + qi) * 16 + l16;
      float inv = 1.0f / (lsum[qi] + lsl[qrow]);
      int row = qt * 64 + qg * 32 + qi * 16 + l16;
#pragma unroll
      for (int j = 0; j < 4; ++j) {
        f4 o;
#pragma unroll
        for (int r = 0; r < 4; ++r)
          o[r] = (acc[qi][j][r] + mrg[qrow * 66 + j * 16 + quad * 4 + r]) * inv;
        *(f4*)(out + (size_t)row * HDIM + h * 64 + j * 16 + quad * 4) = o;
      }
    }
  }
}

extern "C" void kernel_launch(void* const* d_in, const int* in_sizes, int n_in,
                              void* d_out, int out_size, void* d_ws, size_t ws_size,
                              hipStream_t stream) {
  const float* query = (const float*)d_in[0];
  const float* key   = (const float*)d_in[1];
  const float* value = (const float*)d_in[2];
  const float* mask  = (const float*)d_in[3];
  const float* Wq = (const float*)d_in[4];
  const float* bq = (const float*)d_in[5];
  const float* Wk = (const float*)d_in[6];
  const float* bk = (const float*)d_in[7];
  const float* Wv = (const float*)d_in[8];
  const float* bv = (const float*)d_in[9];
  float* out = (float*)d_out;

  // ws usage: exactly 3 * NHEAD*LSEQ*64 bf16 = 18,874,368 bytes (hard limit —
  // writing 4 bytes past this corrupted a pristine input copy in round 2).
  unsigned short* Qb = (unsigned short*)d_ws;                  // [NH][L][64] bf16
  unsigned short* Kb = Qb + (size_t)NHEAD * LSEQ * 64;         // [NH][L][64] bf16
  unsigned short* Vb = Kb + (size_t)NHEAD * LSEQ * 64;         // [NH][64][L] bf16, key-permuted

  proj_gemm<<<576, 256, 0, stream>>>(
      query, key, value, Wq, Wk, Wv, bq, bk, bv, Qb);
  attn<<<dim3(LSEQ / 64, NHEAD), 256, 0, stream>>>(Qb, Kb, Vb, mask, out);
}